// Round 2
// 1469.233 us; speedup vs baseline: 2.2823x; 2.2823x over previous
//
#include <hip/hip_runtime.h>
#include <hip/hip_bf16.h>
#include <stdint.h>

#define BATCH 32
#define LENC  49
#define TSTEPS 24
#define HID   1024
#define VOCAB 32000
#define KSTEP 2048   // per-step x width: context | h
#define NG    4096   // 4*HID gates
#define KCHUNK 8     // split-K chunks for recurrent GEMM

typedef __bf16 bf16_t;
typedef short  s16x8 __attribute__((ext_vector_type(8)));   // bf16x8 bit-pattern (MFMA frag)
typedef float  f32x4 __attribute__((ext_vector_type(4)));

__device__ __forceinline__ float warp_sum(float v){
#pragma unroll
  for (int o = 32; o > 0; o >>= 1) v += __shfl_down(v, o, 64);
  return v;
}
__device__ __forceinline__ float warp_max(float v){
#pragma unroll
  for (int o = 32; o > 0; o >>= 1) v = fmaxf(v, __shfl_down(v, o, 64));
  return v;
}

__device__ __forceinline__ short bf16bits(float f){
  union { bf16_t h; short s; } u; u.h = (bf16_t)f; return u.s;
}
__device__ __forceinline__ float bits2f(short s){
  union { uint32_t u; float f; } b; b.u = ((uint32_t)(uint16_t)s) << 16; return b.f;
}
// split f into hi + lo (bf16 each); f = hi + lo + O(2^-18 |f|)
__device__ __forceinline__ void split1(float f, short& hi, short& lo){
  hi = bf16bits(f);
  lo = bf16bits(f - bits2f(hi));
}
__device__ __forceinline__ void split4(float4 f, short4& hi, short4& lo){
  split1(f.x, hi.x, lo.x); split1(f.y, hi.y, lo.y);
  split1(f.z, hi.z, lo.z); split1(f.w, hi.w, lo.w);
}
__device__ __forceinline__ short4 pack4(float4 f){
  short4 o; o.x = bf16bits(f.x); o.y = bf16bits(f.y); o.z = bf16bits(f.z); o.w = bf16bits(f.w);
  return o;
}
__device__ __forceinline__ s16x8 load8(const bf16_t* p){ return *(const s16x8*)p; }
__device__ __forceinline__ s16x8 load8(const float* p){
  float4 f0 = *(const float4*)p;
  float4 f1 = *(const float4*)(p + 4);
  s16x8 r;
  r[0]=bf16bits(f0.x); r[1]=bf16bits(f0.y); r[2]=bf16bits(f0.z); r[3]=bf16bits(f0.w);
  r[4]=bf16bits(f1.x); r[5]=bf16bits(f1.y); r[6]=bf16bits(f1.z); r[7]=bf16bits(f1.w);
  return r;
}
__device__ __forceinline__ void load8split(const float* p, s16x8& hi, s16x8& lo){
  float4 f0 = *(const float4*)p;
  float4 f1 = *(const float4*)(p + 4);
  short h, l;
  split1(f0.x, h, l); hi[0]=h; lo[0]=l;  split1(f0.y, h, l); hi[1]=h; lo[1]=l;
  split1(f0.z, h, l); hi[2]=h; lo[2]=l;  split1(f0.w, h, l); hi[3]=h; lo[3]=l;
  split1(f1.x, h, l); hi[4]=h; lo[4]=l;  split1(f1.y, h, l); hi[5]=h; lo[5]=l;
  split1(f1.z, h, l); hi[6]=h; lo[6]=l;  split1(f1.w, h, l); hi[7]=h; lo[7]=l;
}

// ---- init: zero h, c ----
__global__ void k_init(float* __restrict__ hbuf, float* __restrict__ cbuf){
  int i = blockIdx.x * 256 + threadIdx.x;       // 0 .. 32767
  hbuf[i] = 0.f;
  cbuf[i] = 0.f;
}

// ---- split [W_ih_ctx | W_hh] rows into hi/lo bf16 [4096][2048] ----
__global__ void k_wsplit(const float* __restrict__ wih, const float* __restrict__ whh,
                         bf16_t* __restrict__ whi, bf16_t* __restrict__ wlo){
  int n = blockIdx.x;                           // 0..4095
  for (int k4 = threadIdx.x; k4 < 512; k4 += 256){
    float4 f;
    if (k4 < 256) f = ((const float4*)(wih + (size_t)n * 2048))[k4];        // ctx cols 0..1023
    else          f = ((const float4*)(whh + (size_t)n * 1024))[k4 - 256];  // h   cols 0..1023
    short4 h4, l4;
    split4(f, h4, l4);
    ((short4*)(whi + (size_t)n * KSTEP))[k4] = h4;
    ((short4*)(wlo + (size_t)n * KSTEP))[k4] = l4;
  }
}

// ---- fp32 -> bf16 bulk convert (n4 = element count / 4) ----
__global__ void k_cvt(const float* __restrict__ src, bf16_t* __restrict__ dst, int n4){
  int i = blockIdx.x * 256 + threadIdx.x;
  if (i < n4){
    float4 f = ((const float4*)src)[i];
    ((short4*)dst)[i] = pack4(f);
  }
}

// ---- one-time: gemb[t][b][n] = emb(t,b) . W_ih[:,1024:2048]^T + b_ih[n] + b_hh[n] ----
// 3-term split in-register (no pre-split buffers needed). grid (32 nblk, 24 t), 256 thr.
__global__ __launch_bounds__(256) void k_gemb(const int* __restrict__ caps,
                                              const float* __restrict__ table,
                                              const float* __restrict__ wih,
                                              const float* __restrict__ bih,
                                              const float* __restrict__ bhh,
                                              float* __restrict__ gemb){
  int tid = threadIdx.x;
  int wave = tid >> 6, lane = tid & 63;
  int quad = lane >> 4, r16 = lane & 15;
  int nwb = blockIdx.x * 128 + wave * 32;
  int t = blockIdx.y;                           // one timestep per m-block (m = t*32 + b)
  const float* rowA = table + (size_t)caps[(size_t)r16 * TSTEPS + t] * HID;
  const float* rowB = table + (size_t)caps[(size_t)(r16 + 16) * TSTEPS + t] * HID;
  f32x4 acc[2][2] = {};

  for (int kk = 0; kk < 32; ++kk){
    int ko = kk * 32 + quad * 8;
    s16x8 a0h, a0l, a1h, a1l, b0h, b0l, b1h, b1l;
    load8split(rowA + ko, a0h, a0l);
    load8split(rowB + ko, a1h, a1l);
    load8split(wih + (size_t)(nwb + r16)      * 2048 + 1024 + ko, b0h, b0l);
    load8split(wih + (size_t)(nwb + 16 + r16) * 2048 + 1024 + ko, b1h, b1l);
    acc[0][0] = __builtin_amdgcn_mfma_f32_16x16x32_bf16(a0h, b0h, acc[0][0], 0, 0, 0);
    acc[0][0] = __builtin_amdgcn_mfma_f32_16x16x32_bf16(a0h, b0l, acc[0][0], 0, 0, 0);
    acc[0][0] = __builtin_amdgcn_mfma_f32_16x16x32_bf16(a0l, b0h, acc[0][0], 0, 0, 0);
    acc[1][0] = __builtin_amdgcn_mfma_f32_16x16x32_bf16(a1h, b0h, acc[1][0], 0, 0, 0);
    acc[1][0] = __builtin_amdgcn_mfma_f32_16x16x32_bf16(a1h, b0l, acc[1][0], 0, 0, 0);
    acc[1][0] = __builtin_amdgcn_mfma_f32_16x16x32_bf16(a1l, b0h, acc[1][0], 0, 0, 0);
    acc[0][1] = __builtin_amdgcn_mfma_f32_16x16x32_bf16(a0h, b1h, acc[0][1], 0, 0, 0);
    acc[0][1] = __builtin_amdgcn_mfma_f32_16x16x32_bf16(a0h, b1l, acc[0][1], 0, 0, 0);
    acc[0][1] = __builtin_amdgcn_mfma_f32_16x16x32_bf16(a0l, b1h, acc[0][1], 0, 0, 0);
    acc[1][1] = __builtin_amdgcn_mfma_f32_16x16x32_bf16(a1h, b1h, acc[1][1], 0, 0, 0);
    acc[1][1] = __builtin_amdgcn_mfma_f32_16x16x32_bf16(a1h, b1l, acc[1][1], 0, 0, 0);
    acc[1][1] = __builtin_amdgcn_mfma_f32_16x16x32_bf16(a1l, b1h, acc[1][1], 0, 0, 0);
  }
#pragma unroll
  for (int mt = 0; mt < 2; ++mt)
#pragma unroll
    for (int nt = 0; nt < 2; ++nt)
#pragma unroll
      for (int r = 0; r < 4; ++r){
        int m = mt * 16 + quad * 4 + r;          // b index
        int n = nwb + nt * 16 + r16;
        gemb[((size_t)t * BATCH + m) * NG + n] = acc[mt][nt][r] + bih[n] + bhh[n];
      }
}

// ---- attention (all fp32): scores, softmax, context; writes split x = [ctx|h] ----
__global__ __launch_bounds__(256) void k_attn(const float* __restrict__ feat,
                                              const float* __restrict__ hbuf,
                                              bf16_t* __restrict__ xh,
                                              bf16_t* __restrict__ xl){
  int b = blockIdx.x;
  __shared__ float sh[HID];
  __shared__ float sw[64];
  int tid = threadIdx.x;
  for (int k = tid; k < HID; k += 256) sh[k] = hbuf[b * HID + k];
  __syncthreads();
  int wave = tid >> 6, lane = tid & 63;
  const float4* fb4 = (const float4*)(feat + (size_t)b * LENC * HID);
  const float4* sh4 = (const float4*)sh;
  for (int l = wave; l < LENC; l += 4){
    float acc = 0.f;
    for (int k4 = lane; k4 < 256; k4 += 64){
      float4 f = fb4[l * 256 + k4];
      float4 h = sh4[k4];
      acc = fmaf(f.x, h.x, acc); acc = fmaf(f.y, h.y, acc);
      acc = fmaf(f.z, h.z, acc); acc = fmaf(f.w, h.w, acc);
    }
    acc = warp_sum(acc);
    if (lane == 0) sw[l] = acc;
  }
  __syncthreads();
  if (tid < 64){
    float s = (tid < LENC) ? sw[tid] : -1e30f;
    float m = warp_max(s);
    m = __shfl(m, 0, 64);
    float e = (tid < LENC) ? expf(s - m) : 0.f;
    float ssum = warp_sum(e);
    ssum = __shfl(ssum, 0, 64);
    if (tid < LENC) sw[tid] = e / ssum;
  }
  __syncthreads();
  // context -> x[b][0:1024] (split)
  {
    int k4 = tid;                               // 0..255
    float4 a = make_float4(0.f, 0.f, 0.f, 0.f);
#pragma unroll 7
    for (int l = 0; l < LENC; ++l){
      float wl = sw[l];
      float4 f = fb4[l * 256 + k4];
      a.x = fmaf(wl, f.x, a.x); a.y = fmaf(wl, f.y, a.y);
      a.z = fmaf(wl, f.z, a.z); a.w = fmaf(wl, f.w, a.w);
    }
    short4 h4, l4;
    split4(a, h4, l4);
    ((short4*)(xh + (size_t)b * KSTEP))[k4] = h4;
    ((short4*)(xl + (size_t)b * KSTEP))[k4] = l4;
  }
  // h -> x[b][1024:2048] (split)
  {
    float4 f = sh4[tid];
    short4 h4, l4;
    split4(f, h4, l4);
    ((short4*)(xh + (size_t)b * KSTEP + 1024))[tid] = h4;
    ((short4*)(xl + (size_t)b * KSTEP + 1024))[tid] = l4;
  }
}

// ---- recurrent gates GEMM, split-bf16 (3-term), split-K over 8 chunks ----
// grid (64 n-tiles, 8 k-chunks), 128 thr (2 waves: n-sub). Writes fp32 partials.
template <bool CAT>
__global__ __launch_bounds__(128) void k_ggemm(const bf16_t* __restrict__ xh,
                                               const bf16_t* __restrict__ xl,
                                               const bf16_t* __restrict__ whi,
                                               const bf16_t* __restrict__ wlo,
                                               const float* __restrict__ wih,
                                               const float* __restrict__ whh,
                                               float* __restrict__ gbuf){
  int tid = threadIdx.x;
  int wave = tid >> 6, lane = tid & 63;
  int quad = lane >> 4, r16 = lane & 15;
  int nwb = blockIdx.x * 64 + wave * 32;        // this wave's n-base
  int kbase = blockIdx.y * (KSTEP / KCHUNK);    // 256-wide K chunk
  f32x4 acc[2][2] = {};

#pragma unroll
  for (int kk = 0; kk < 8; ++kk){
    int ko = kbase + kk * 32 + quad * 8;
    s16x8 a0h = load8(xh + (size_t)r16        * KSTEP + ko);
    s16x8 a0l = load8(xl + (size_t)r16        * KSTEP + ko);
    s16x8 a1h = load8(xh + (size_t)(r16 + 16) * KSTEP + ko);
    s16x8 a1l = load8(xl + (size_t)(r16 + 16) * KSTEP + ko);
    s16x8 b0h, b0l, b1h, b1l;
    if (CAT){
      b0h = load8(whi + (size_t)(nwb + r16)      * KSTEP + ko);
      b0l = load8(wlo + (size_t)(nwb + r16)      * KSTEP + ko);
      b1h = load8(whi + (size_t)(nwb + 16 + r16) * KSTEP + ko);
      b1l = load8(wlo + (size_t)(nwb + 16 + r16) * KSTEP + ko);
    } else {
      if (ko < 1024){
        load8split(wih + (size_t)(nwb + r16)      * 2048 + ko, b0h, b0l);
        load8split(wih + (size_t)(nwb + 16 + r16) * 2048 + ko, b1h, b1l);
      } else {
        load8split(whh + (size_t)(nwb + r16)      * 1024 + (ko - 1024), b0h, b0l);
        load8split(whh + (size_t)(nwb + 16 + r16) * 1024 + (ko - 1024), b1h, b1l);
      }
    }
    // hi*hi + hi*lo + lo*hi (lo*lo dropped: 2^-18)
    acc[0][0] = __builtin_amdgcn_mfma_f32_16x16x32_bf16(a0h, b0h, acc[0][0], 0, 0, 0);
    acc[0][0] = __builtin_amdgcn_mfma_f32_16x16x32_bf16(a0h, b0l, acc[0][0], 0, 0, 0);
    acc[0][0] = __builtin_amdgcn_mfma_f32_16x16x32_bf16(a0l, b0h, acc[0][0], 0, 0, 0);
    acc[1][0] = __builtin_amdgcn_mfma_f32_16x16x32_bf16(a1h, b0h, acc[1][0], 0, 0, 0);
    acc[1][0] = __builtin_amdgcn_mfma_f32_16x16x32_bf16(a1h, b0l, acc[1][0], 0, 0, 0);
    acc[1][0] = __builtin_amdgcn_mfma_f32_16x16x32_bf16(a1l, b0h, acc[1][0], 0, 0, 0);
    acc[0][1] = __builtin_amdgcn_mfma_f32_16x16x32_bf16(a0h, b1h, acc[0][1], 0, 0, 0);
    acc[0][1] = __builtin_amdgcn_mfma_f32_16x16x32_bf16(a0h, b1l, acc[0][1], 0, 0, 0);
    acc[0][1] = __builtin_amdgcn_mfma_f32_16x16x32_bf16(a0l, b1h, acc[0][1], 0, 0, 0);
    acc[1][1] = __builtin_amdgcn_mfma_f32_16x16x32_bf16(a1h, b1h, acc[1][1], 0, 0, 0);
    acc[1][1] = __builtin_amdgcn_mfma_f32_16x16x32_bf16(a1h, b1l, acc[1][1], 0, 0, 0);
    acc[1][1] = __builtin_amdgcn_mfma_f32_16x16x32_bf16(a1l, b1h, acc[1][1], 0, 0, 0);
  }
  // D layout: row m = quad*4 + r (within 16), col n' = r16
#pragma unroll
  for (int mt = 0; mt < 2; ++mt)
#pragma unroll
    for (int nt = 0; nt < 2; ++nt)
#pragma unroll
      for (int r = 0; r < 4; ++r){
        int m = mt * 16 + quad * 4 + r;          // batch index
        int n = nwb + nt * 16 + r16;             // gate row index
        gbuf[((size_t)blockIdx.y * BATCH + m) * NG + n] = acc[mt][nt][r];
      }
}

// ---- LSTM cell update: sum split-K partials + gemb (biases folded there) ----
__global__ void k_cell(const float* __restrict__ gbuf,
                       const float* __restrict__ gemb,
                       float* __restrict__ hbuf, float* __restrict__ cbuf,
                       bf16_t* __restrict__ hall, int t){
  int i = blockIdx.x * 256 + threadIdx.x;       // 0..32767
  int b = i >> 10, j = i & 1023;
  const float* ge = gemb + ((size_t)t * BATCH + b) * NG;
  float gi = ge[j], gf = ge[1024 + j], gg = ge[2048 + j], go = ge[3072 + j];
#pragma unroll
  for (int c = 0; c < KCHUNK; ++c){
    const float* g = gbuf + ((size_t)c * BATCH + b) * NG;
    gi += g[j]; gf += g[1024 + j]; gg += g[2048 + j]; go += g[3072 + j];
  }
  float c_old = cbuf[i];
  float si = 1.f / (1.f + expf(-gi));
  float sf = 1.f / (1.f + expf(-gf));
  float so = 1.f / (1.f + expf(-go));
  float c_new = sf * c_old + si * tanhf(gg);
  float h_new = so * tanhf(c_new);
  cbuf[i] = c_new;
  hbuf[i] = h_new;
  hall[((size_t)t * BATCH + b) * HID + j] = (bf16_t)h_new;
}

// ---- batched logits GEMM: [768 x 1024] x [1024 x 32000]^T + b_out (fp32 out) ----
// grid (6 m-tiles, 250 n-tiles): the 6 blocks sharing a W_out tile are
// dispatch-adjacent -> concurrent -> one HBM fetch of the tile instead of ~3.
template <typename WT>
__global__ __launch_bounds__(256) void k_logits(const bf16_t* __restrict__ hall,
                                                const WT* __restrict__ wout,
                                                const float* __restrict__ bout,
                                                float* __restrict__ out){
  int m0 = blockIdx.x * 128;
  int n0 = blockIdx.y * 128;
  int tid = threadIdx.x;
  int wave = tid >> 6, lane = tid & 63;
  int wm = wave >> 1, wn = wave & 1;
  int quad = lane >> 4, r16 = lane & 15;
  f32x4 acc[4][4] = {};

  for (int kk = 0; kk < 32; ++kk){
    int k0 = kk * 32 + quad * 8;
    s16x8 af[4], bfr[4];
#pragma unroll
    for (int mt = 0; mt < 4; ++mt){
      int m = m0 + wm * 64 + mt * 16 + r16;
      af[mt] = load8(hall + (size_t)m * HID + k0);
    }
#pragma unroll
    for (int nt = 0; nt < 4; ++nt){
      int n = n0 + wn * 64 + nt * 16 + r16;
      bfr[nt] = load8(wout + (size_t)n * HID + k0);
    }
#pragma unroll
    for (int mt = 0; mt < 4; ++mt)
#pragma unroll
      for (int nt = 0; nt < 4; ++nt)
        acc[mt][nt] = __builtin_amdgcn_mfma_f32_16x16x32_bf16(af[mt], bfr[nt], acc[mt][nt], 0, 0, 0);
  }

#pragma unroll
  for (int mt = 0; mt < 4; ++mt){
    int mbase = m0 + wm * 64 + mt * 16 + quad * 4;
#pragma unroll
    for (int r = 0; r < 4; ++r){
      int m = mbase + r;
      int tt = m >> 5, b = m & 31;              // hall row m = t*32 + b
      size_t outrow = ((size_t)b * TSTEPS + tt) * VOCAB;
#pragma unroll
      for (int nt = 0; nt < 4; ++nt){
        int n = n0 + wn * 64 + nt * 16 + r16;
        out[outrow + n] = acc[mt][nt][r] + bout[n];
      }
    }
  }
}

extern "C" void kernel_launch(void* const* d_in, const int* in_sizes, int n_in,
                              void* d_out, int out_size, void* d_ws, size_t ws_size,
                              hipStream_t stream) {
  const float* feat  = (const float*)d_in[0];
  const int*   caps  = (const int*)d_in[1];
  const float* table = (const float*)d_in[2];
  const float* wih   = (const float*)d_in[3];
  const float* whh   = (const float*)d_in[4];
  const float* bih   = (const float*)d_in[5];
  const float* bhh   = (const float*)d_in[6];
  const float* wout  = (const float*)d_in[7];
  const float* bout  = (const float*)d_in[8];
  float* out = (float*)d_out;
  (void)in_sizes; (void)n_in; (void)out_size;

  char* ws = (char*)d_ws;
  bf16_t* hall  = (bf16_t*)(ws);                 //  1,572,864 ->  1,572,864
  bf16_t* xh    = (bf16_t*)(ws + 1572864);       //    131,072 ->  1,703,936
  bf16_t* xl    = (bf16_t*)(ws + 1703936);       //    131,072 ->  1,835,008
  float*  hbuf  = (float*)(ws + 1835008);        //    131,072 ->  1,966,080
  float*  cbuf  = (float*)(ws + 1966080);        //    131,072 ->  2,097,152
  float*  gbuf  = (float*)(ws + 2097152);        //  4,194,304 ->  6,291,456  (8 split-K partials)
  float*  gemb  = (float*)(ws + 6291456);        // 12,582,912 -> 18,874,368  (precomputed emb gates + biases)
  bf16_t* whi   = (bf16_t*)(ws + 18874368);      // 16,777,216 -> 35,651,584
  bf16_t* wlo   = (bf16_t*)(ws + 35651584);      // 16,777,216 -> 52,428,800
  bf16_t* woutb = (bf16_t*)(ws + 52428800);      // 65,536,000 -> 117,964,800

  const bool useW    = (ws_size >= (size_t)52428800);
  const bool useWout = (ws_size >= (size_t)117964800);

  k_init<<<dim3(128), dim3(256), 0, stream>>>(hbuf, cbuf);
  if (useW)
    k_wsplit<<<dim3(NG), dim3(256), 0, stream>>>(wih, whh, whi, wlo);
  if (useWout)
    k_cvt<<<dim3(32000), dim3(256), 0, stream>>>(wout, woutb, VOCAB * HID / 4);
  // one-time: embedding contribution to gates for all timesteps (+ biases folded in)
  k_gemb<<<dim3(32, TSTEPS), dim3(256), 0, stream>>>(caps, table, wih, bih, bhh, gemb);

  for (int t = 0; t < TSTEPS; ++t){
    k_attn<<<dim3(BATCH), dim3(256), 0, stream>>>(feat, hbuf, xh, xl);
    if (useW)
      k_ggemm<true><<<dim3(64, KCHUNK), dim3(128), 0, stream>>>(xh, xl, whi, wlo, wih, whh, gbuf);
    else
      k_ggemm<false><<<dim3(64, KCHUNK), dim3(128), 0, stream>>>(xh, xl, whi, wlo, wih, whh, gbuf);
    k_cell<<<dim3(128), dim3(256), 0, stream>>>(gbuf, gemb, hbuf, cbuf, hall, t);
  }
  if (useWout)
    k_logits<bf16_t><<<dim3(6, VOCAB / 128), dim3(256), 0, stream>>>(hall, woutb, bout, out);
  else
    k_logits<float><<<dim3(6, VOCAB / 128), dim3(256), 0, stream>>>(hall, wout, bout, out);
}